// Round 1
// 821.219 us; speedup vs baseline: 1.0192x; 1.0192x over previous
//
#include <hip/hip_runtime.h>
#include <hip/hip_bf16.h>
#include <stdint.h>

typedef __attribute__((ext_vector_type(8))) short short8;
typedef __attribute__((ext_vector_type(4))) float floatx4;

#define ROWS 64            // rows per block
#define NTHREADS 512       // 8 waves
#define KDIM 512
#define OUTC 1025          // 1 + 512 + 512
#define LDSS 520           // LDS row stride in bf16 elems (1040 B, 2-way-free bank stride)

__device__ __forceinline__ ushort f2b(float f) {
    // round-to-nearest-even fp32 -> bf16
    union { float f; uint32_t u; } c; c.f = f;
    return (ushort)((c.u + 0x7fffu + ((c.u >> 16) & 1u)) >> 16);
}

// One-time per launch: Wt[n*512 + k] = bf16(W[k*512 + n])  (MFMA B-operand wants k
// contiguous per lane at fixed n). 0.5 MiB output, L2-resident afterwards.
__global__ void wt_kernel(const float* __restrict__ w, ushort* __restrict__ wt) {
    int i = blockIdx.x * 256 + threadIdx.x;   // 262144 total
    int k = i >> 9, n = i & 511;
    wt[n * KDIM + k] = f2b(w[i]);
}

__global__ __launch_bounds__(NTHREADS, 4)
void lola_kernel(const float* __restrict__ x, const ushort* __restrict__ wt,
                 float* __restrict__ out) {
    __shared__ ushort lds[ROWS * LDSS];       // 65 KiB -> 2 blocks/CU
    const int t = threadIdx.x;
    const long row0 = (long)blockIdx.x * ROWS;
    const int wave = t >> 6, lane = t & 63;

    // ---- staging: wave w owns rows 8w..8w+7; lane-major scalar access ----
    // Every global load/store instruction covers 256 CONTIGUOUS bytes (100%
    // write-request density; the old float4-component stores were 4B @ 16B
    // stride = 25% density on a 256 MiB stream).
    {
#pragma unroll 2
        for (int rr = 0; rr < 8; ++rr) {
            const int r = wave * 8 + rr;
            const float* __restrict__ xr = x + (row0 + r) * (long)KDIM;
            float* __restrict__ orow = out + (row0 + r) * (long)OUTC;
            float v[8];
            float s = 0.f;
#pragma unroll
            for (int i = 0; i < 8; ++i) {
                v[i] = xr[lane + 64 * i];     // 256 B/instr, contiguous
                s += v[i];
            }
#pragma unroll
            for (int i = 0; i < 8; ++i) {
                lds[r * LDSS + lane + 64 * i] = f2b(v[i]);  // ds_write_b16, 2 lanes/bank = free
                orow[1 + lane + 64 * i] = v[i];             // 256 B/instr, contiguous
            }
            // full-wave sum reduction for out[:, 0]
            s += __shfl_xor(s, 1);
            s += __shfl_xor(s, 2);
            s += __shfl_xor(s, 4);
            s += __shfl_xor(s, 8);
            s += __shfl_xor(s, 16);
            s += __shfl_xor(s, 32);
            if (lane == 0) orow[0] = s;
        }
    }
    __syncthreads();

    // ---- GEMM: out[:, 513:1025] = x @ W via bf16 MFMA (verified layout) ----
    // wave w owns n-strip [64w, 64w+64); 4 m-tiles x 4 n-tiles of 16x16x32
    const int l15 = lane & 15, quad = lane >> 4;
    const ushort* __restrict__ wbase = wt + (size_t)(wave * 64) * KDIM;
    floatx4 acc[4][4] = {};

    for (int ks = 0; ks < 16; ++ks) {         // K = 16 steps of 32
        short8 a[4], b[4];
#pragma unroll
        for (int mt = 0; mt < 4; ++mt)        // A[m=l15][k=quad*8+j], 16 B ds_read_b128
            a[mt] = *(const short8*)&lds[(mt * 16 + l15) * LDSS + ks * 32 + quad * 8];
#pragma unroll
        for (int nt = 0; nt < 4; ++nt)        // B[k][n]: Wt is [n][k], 16 B L2 load
            b[nt] = *(const short8*)&wbase[(size_t)(nt * 16 + l15) * KDIM + ks * 32 + quad * 8];
#pragma unroll
        for (int mt = 0; mt < 4; ++mt)
#pragma unroll
            for (int nt = 0; nt < 4; ++nt)
                acc[mt][nt] = __builtin_amdgcn_mfma_f32_16x16x32_bf16(a[mt], b[nt], acc[mt][nt], 0, 0, 0);
    }

    // epilogue: C/D layout col = lane&15 (n), row = quad*4 + reg (m).
    // Per instr: 4 rows x 64 contiguous bytes; adjacent nt instrs tile 256-B
    // runs per row, so L2 merges into full lines.
#pragma unroll
    for (int mt = 0; mt < 4; ++mt)
#pragma unroll
        for (int nt = 0; nt < 4; ++nt)
#pragma unroll
            for (int rg = 0; rg < 4; ++rg) {
                const long grow = row0 + mt * 16 + quad * 4 + rg;
                const int gcol = 513 + wave * 64 + nt * 16 + l15;
                out[grow * OUTC + gcol] = acc[mt][nt][rg];
            }
}

extern "C" void kernel_launch(void* const* d_in, const int* in_sizes, int n_in,
                              void* d_out, int out_size, void* d_ws, size_t ws_size,
                              hipStream_t stream) {
    const float* x = (const float*)d_in[0];     // (32768, 4, 512) fp32
    const float* w = (const float*)d_in[1];     // (512, 512) fp32
    float* out = (float*)d_out;                 // (32768, 4, 1025) fp32
    ushort* wt = (ushort*)d_ws;                 // 512*512 bf16 = 512 KiB scratch

    const long rows = (long)in_sizes[0] / KDIM; // 131072
    wt_kernel<<<(512 * 512) / 256, 256, 0, stream>>>(w, wt);
    lola_kernel<<<(int)(rows / ROWS), NTHREADS, 0, stream>>>(x, wt, out);
}